// Round 1
// baseline (17759.912 us; speedup 1.0000x reference)
//
#include <hip/hip_runtime.h>
#include <stdint.h>

#define TT  512
#define BPB 4

__device__ __forceinline__ uint32_t f2bf(float f) {
    uint32_t u = __float_as_uint(f);
    return (u + 0x7FFFu + ((u >> 16) & 1u)) >> 16;   // RNE to bf16
}
__device__ __forceinline__ float sigm(float x) {
    float e = __builtin_amdgcn_exp2f(-1.4426950408889634f * x);
    return __builtin_amdgcn_rcpf(1.0f + e);
}
__device__ __forceinline__ float rdlane(float v, int k) {
    return __uint_as_float((uint32_t)__builtin_amdgcn_readlane((int)__float_as_uint(v), k));
}

// 256 blocks x 1024 threads. Block owns BPB=4 batch elements.
// Wave role: l = wave>>2 (layer), gi = wave&3 (gate group). Pipelined over layers:
// layer l works on local t = s - l. h handoff between layers via LDS (parity dbuf).
__global__ __launch_bounds__(1024, 4) void lstm_fused(
    const float* __restrict__ x,
    const float* __restrict__ Wx0, const float* __restrict__ U0, const float* __restrict__ b0,
    const float* __restrict__ Wx1, const float* __restrict__ U1, const float* __restrict__ b1,
    const float* __restrict__ Wx2, const float* __restrict__ U2, const float* __restrict__ b2,
    const float* __restrict__ Wx3, const float* __restrict__ U3, const float* __restrict__ b3,
    const float* __restrict__ Wd,  const float* __restrict__ bd,
    float* __restrict__ out)
{
    __shared__ float z_s[4 * 4 * BPB * 64];   // [l][gi][br][lane]  16 KB
    __shared__ float hb [4 * 2 * BPB * 64];   // [l][parity][br][lane] 8 KB (l=0..2 used)
    __shared__ float x_s[BPB * TT];           // 8 KB

    const int tid  = threadIdx.x;
    const int lane = tid & 63;
    const int wv   = tid >> 6;
    const int l    = wv >> 2;
    const int gi   = wv & 3;
    const int g    = (gi << 6) | lane;        // this thread's gate column in [0,256)
    const int b0i  = blockIdx.x * BPB;

    // stage x for this block's batch rows
    for (int idx = tid; idx < BPB * TT; idx += 1024) {
        int br = idx >> 9, t = idx & (TT - 1);
        x_s[idx] = x[(b0i + br) * TT + t];
    }

    const float *Uw, *bw, *Wxw;
    if      (l == 0) { Uw = U0; bw = b0; Wxw = Wx0; }
    else if (l == 1) { Uw = U1; bw = b1; Wxw = Wx1; }
    else if (l == 2) { Uw = U2; bw = b2; Wxw = Wx2; }
    else             { Uw = U3; bw = b3; Wxw = Wx3; }

    // thread-stationary weights, bf16-packed pairs (fp32 won't fit 128 VGPRs)
    uint32_t u_pk[32];
    #pragma unroll
    for (int kp = 0; kp < 32; ++kp) {
        float a = Uw[(2 * kp) * 256 + g];
        float b = Uw[(2 * kp + 1) * 256 + g];
        u_pk[kp] = f2bf(a) | (f2bf(b) << 16);
    }
    uint32_t w_pk[32];
    if (l > 0) {
        #pragma unroll
        for (int kp = 0; kp < 32; ++kp) {
            float a = Wxw[(2 * kp) * 256 + g];
            float b = Wxw[(2 * kp + 1) * 256 + g];
            w_pk[kp] = f2bf(a) | (f2bf(b) << 16);
        }
    } else {
        #pragma unroll
        for (int kp = 0; kp < 32; ++kp) w_pk[kp] = 0;
    }
    const float bias = bw[g];
    const float wx0w = (l == 0) ? Wxw[g] : 0.f;   // layer 0: F=1, fp32 scalar weight

    float h_r[BPB], c_r[BPB];
    #pragma unroll
    for (int br = 0; br < BPB; ++br) { h_r[br] = 0.f; c_r[br] = 0.f; }

    __syncthreads();

    for (int s = 0; s < TT + 3; ++s) {
        const int t = s - l;
        const bool active = (t >= 0) && (t < TT);

        if (active) {
            float acc[BPB];
            #pragma unroll
            for (int br = 0; br < BPB; ++br) acc[br] = bias;

            if (l == 0) {
                #pragma unroll
                for (int br = 0; br < BPB; ++br)
                    acc[br] += x_s[(br << 9) + t] * wx0w;
            } else {
                // input = previous layer's h at same local t (written last step, parity (s-1)&1)
                float xp[BPB];
                const float* src = hb + ((((l - 1) * 2 + ((s + 1) & 1)) * BPB) << 6);
                #pragma unroll
                for (int br = 0; br < BPB; ++br) xp[br] = src[(br << 6) + lane];
                #pragma unroll
                for (int kp = 0; kp < 32; ++kp) {
                    uint32_t w = w_pk[kp];
                    float w0 = __uint_as_float(w << 16);
                    float w1 = __uint_as_float(w & 0xffff0000u);
                    #pragma unroll
                    for (int br = 0; br < BPB; ++br) {
                        acc[br] += rdlane(xp[br], 2 * kp) * w0;
                        acc[br] += rdlane(xp[br], 2 * kp + 1) * w1;
                    }
                }
            }
            // recurrent part: h broadcast via v_readlane, U in registers
            #pragma unroll
            for (int kp = 0; kp < 32; ++kp) {
                uint32_t w = u_pk[kp];
                float w0 = __uint_as_float(w << 16);
                float w1 = __uint_as_float(w & 0xffff0000u);
                #pragma unroll
                for (int br = 0; br < BPB; ++br) {
                    acc[br] += rdlane(h_r[br], 2 * kp) * w0;
                    acc[br] += rdlane(h_r[br], 2 * kp + 1) * w1;
                }
            }
            float* zw = z_s + (((l * 4 + gi) * BPB) << 6);
            #pragma unroll
            for (int br = 0; br < BPB; ++br) zw[(br << 6) + lane] = acc[br];
        }

        __syncthreads();

        if (active) {
            // every wave of layer l redundantly combines gates for all br
            // (keeps h in registers of every wave -> readlane source next step)
            const float* zl = z_s + ((l * 4 * BPB) << 6);
            #pragma unroll
            for (int br = 0; br < BPB; ++br) {
                float zi = zl[((0 * BPB + br) << 6) + lane];
                float zf = zl[((1 * BPB + br) << 6) + lane];
                float zg = zl[((2 * BPB + br) << 6) + lane];
                float zo = zl[((3 * BPB + br) << 6) + lane];
                float c  = sigm(zf) * c_r[br] + sigm(zi) * fmaxf(zg, 0.f);
                float h  = sigm(zo) * fmaxf(c, 0.f);
                c_r[br] = c; h_r[br] = h;
            }
            if (l < 3) {
                // publish h for next layer (wave gi writes batch row gi)
                float* dst = hb + (((l * 2 + (s & 1)) * BPB) << 6);
                dst[(gi << 6) + lane] = h_r[gi];
            } else if (t == TT - 1) {
                // final dense: wave gi handles batch b0i+gi
                float v = h_r[gi] * Wd[lane];
                #pragma unroll
                for (int off = 32; off > 0; off >>= 1)
                    v += __shfl_down(v, off, 64);
                if (lane == 0) out[b0i + gi] = v + bd[0];
            }
        }

        __syncthreads();
    }
}

extern "C" void kernel_launch(void* const* d_in, const int* in_sizes, int n_in,
                              void* d_out, int out_size, void* d_ws, size_t ws_size,
                              hipStream_t stream) {
    const float* x   = (const float*)d_in[0];
    const float* Wx0 = (const float*)d_in[1];
    const float* U0  = (const float*)d_in[2];
    const float* b0  = (const float*)d_in[3];
    const float* Wx1 = (const float*)d_in[4];
    const float* U1  = (const float*)d_in[5];
    const float* b1  = (const float*)d_in[6];
    const float* Wx2 = (const float*)d_in[7];
    const float* U2  = (const float*)d_in[8];
    const float* b2  = (const float*)d_in[9];
    const float* Wx3 = (const float*)d_in[10];
    const float* U3  = (const float*)d_in[11];
    const float* b3  = (const float*)d_in[12];
    const float* Wd  = (const float*)d_in[13];
    const float* bd  = (const float*)d_in[14];
    float* out = (float*)d_out;

    hipLaunchKernelGGL(lstm_fused, dim3(256), dim3(1024), 0, stream,
                       x, Wx0, U0, b0, Wx1, U1, b1, Wx2, U2, b2, Wx3, U3, b3,
                       Wd, bd, out);
}

// Round 2
// 17640.178 us; speedup vs baseline: 1.0068x; 1.0068x over previous
//
#include <hip/hip_runtime.h>
#include <stdint.h>

#define TT  512
#define BPB 4

__device__ __forceinline__ uint32_t f2bf(float f) {
    uint32_t u = __float_as_uint(f);
    return (u + 0x7FFFu + ((u >> 16) & 1u)) >> 16;   // RNE to bf16
}
__device__ __forceinline__ float sigm(float x) {
    float e = __builtin_amdgcn_exp2f(-1.4426950408889634f * x);
    return __builtin_amdgcn_rcpf(1.0f + e);
}
__device__ __forceinline__ float rdlane(float v, int k) {
    return __uint_as_float((uint32_t)__builtin_amdgcn_readlane((int)__float_as_uint(v), k));
}

// 256 blocks x 1024 threads. Block owns BPB=4 batch elements.
// Wave role: l = wave>>2 (layer), gi = wave&3 (gate group). Pipelined over layers:
// layer l works on local t = s - l. h handoff between layers via LDS (parity dbuf).
//
// amdgpu_waves_per_eu(4,4): pin the register budget to 128 VGPRs (512/4).
// R1 post-mortem: __launch_bounds__(1024,4) let the allocator target 8 waves/EU
// (64 VGPRs) and spill the 64-reg weight cache to scratch -> 44 GB HBM fetch.
__global__ __launch_bounds__(1024)
__attribute__((amdgpu_waves_per_eu(4, 4)))
void lstm_fused(
    const float* __restrict__ x,
    const float* __restrict__ Wx0, const float* __restrict__ U0, const float* __restrict__ b0,
    const float* __restrict__ Wx1, const float* __restrict__ U1, const float* __restrict__ b1,
    const float* __restrict__ Wx2, const float* __restrict__ U2, const float* __restrict__ b2,
    const float* __restrict__ Wx3, const float* __restrict__ U3, const float* __restrict__ b3,
    const float* __restrict__ Wd,  const float* __restrict__ bd,
    float* __restrict__ out)
{
    __shared__ float z_s[4 * 4 * BPB * 64];   // [l][gi][br][lane]  16 KB
    __shared__ float hb [4 * 2 * BPB * 64];   // [l][parity][br][lane] 8 KB (l=0..2 used)
    __shared__ float x_s[BPB * TT];           // 8 KB

    const int tid  = threadIdx.x;
    const int lane = tid & 63;
    const int wv   = tid >> 6;
    const int l    = wv >> 2;
    const int gi   = wv & 3;
    const int g    = (gi << 6) | lane;        // this thread's gate column in [0,256)
    const int b0i  = blockIdx.x * BPB;

    // stage x for this block's batch rows
    for (int idx = tid; idx < BPB * TT; idx += 1024) {
        int br = idx >> 9, t = idx & (TT - 1);
        x_s[idx] = x[(b0i + br) * TT + t];
    }

    const float *Uw, *bw, *Wxw;
    if      (l == 0) { Uw = U0; bw = b0; Wxw = Wx0; }
    else if (l == 1) { Uw = U1; bw = b1; Wxw = Wx1; }
    else if (l == 2) { Uw = U2; bw = b2; Wxw = Wx2; }
    else             { Uw = U3; bw = b3; Wxw = Wx3; }

    // thread-stationary weights, bf16-packed pairs (fp32 won't fit 128 VGPRs)
    uint32_t u_pk[32];
    #pragma unroll
    for (int kp = 0; kp < 32; ++kp) {
        float a = Uw[(2 * kp) * 256 + g];
        float b = Uw[(2 * kp + 1) * 256 + g];
        u_pk[kp] = f2bf(a) | (f2bf(b) << 16);
    }
    uint32_t w_pk[32];
    if (l > 0) {
        #pragma unroll
        for (int kp = 0; kp < 32; ++kp) {
            float a = Wxw[(2 * kp) * 256 + g];
            float b = Wxw[(2 * kp + 1) * 256 + g];
            w_pk[kp] = f2bf(a) | (f2bf(b) << 16);
        }
    } else {
        #pragma unroll
        for (int kp = 0; kp < 32; ++kp) w_pk[kp] = 0;
    }
    const float bias = bw[g];
    const float wx0w = (l == 0) ? Wxw[g] : 0.f;   // layer 0: F=1, fp32 scalar weight

    float h_r[BPB], c_r[BPB];
    #pragma unroll
    for (int br = 0; br < BPB; ++br) { h_r[br] = 0.f; c_r[br] = 0.f; }

    __syncthreads();

    for (int s = 0; s < TT + 3; ++s) {
        const int t = s - l;
        const bool active = (t >= 0) && (t < TT);

        if (active) {
            float acc[BPB];
            #pragma unroll
            for (int br = 0; br < BPB; ++br) acc[br] = bias;

            if (l == 0) {
                #pragma unroll
                for (int br = 0; br < BPB; ++br)
                    acc[br] += x_s[(br << 9) + t] * wx0w;
            } else {
                // input = previous layer's h at same local t (written last step, parity (s-1)&1)
                float xp[BPB];
                const float* src = hb + ((((l - 1) * 2 + ((s + 1) & 1)) * BPB) << 6);
                #pragma unroll
                for (int br = 0; br < BPB; ++br) xp[br] = src[(br << 6) + lane];
                #pragma unroll
                for (int kp = 0; kp < 32; ++kp) {
                    uint32_t w = w_pk[kp];
                    float w0 = __uint_as_float(w << 16);
                    float w1 = __uint_as_float(w & 0xffff0000u);
                    #pragma unroll
                    for (int br = 0; br < BPB; ++br) {
                        acc[br] += rdlane(xp[br], 2 * kp) * w0;
                        acc[br] += rdlane(xp[br], 2 * kp + 1) * w1;
                    }
                }
            }
            // recurrent part: h broadcast via v_readlane, U in registers
            #pragma unroll
            for (int kp = 0; kp < 32; ++kp) {
                uint32_t w = u_pk[kp];
                float w0 = __uint_as_float(w << 16);
                float w1 = __uint_as_float(w & 0xffff0000u);
                #pragma unroll
                for (int br = 0; br < BPB; ++br) {
                    acc[br] += rdlane(h_r[br], 2 * kp) * w0;
                    acc[br] += rdlane(h_r[br], 2 * kp + 1) * w1;
                }
            }
            float* zw = z_s + (((l * 4 + gi) * BPB) << 6);
            #pragma unroll
            for (int br = 0; br < BPB; ++br) zw[(br << 6) + lane] = acc[br];
        }

        __syncthreads();

        if (active) {
            // every wave of layer l redundantly combines gates for all br
            // (keeps h in registers of every wave -> readlane source next step)
            const float* zl = z_s + ((l * 4 * BPB) << 6);
            #pragma unroll
            for (int br = 0; br < BPB; ++br) {
                float zi = zl[((0 * BPB + br) << 6) + lane];
                float zf = zl[((1 * BPB + br) << 6) + lane];
                float zg = zl[((2 * BPB + br) << 6) + lane];
                float zo = zl[((3 * BPB + br) << 6) + lane];
                float c  = sigm(zf) * c_r[br] + sigm(zi) * fmaxf(zg, 0.f);
                float h  = sigm(zo) * fmaxf(c, 0.f);
                c_r[br] = c; h_r[br] = h;
            }
            if (l < 3) {
                // publish h for next layer (wave gi writes batch row gi)
                float* dst = hb + (((l * 2 + (s & 1)) * BPB) << 6);
                dst[(gi << 6) + lane] = h_r[gi];
            } else if (t == TT - 1) {
                // final dense: wave gi handles batch b0i+gi
                float v = h_r[gi] * Wd[lane];
                #pragma unroll
                for (int off = 32; off > 0; off >>= 1)
                    v += __shfl_down(v, off, 64);
                if (lane == 0) out[b0i + gi] = v + bd[0];
            }
        }

        __syncthreads();
    }
}

extern "C" void kernel_launch(void* const* d_in, const int* in_sizes, int n_in,
                              void* d_out, int out_size, void* d_ws, size_t ws_size,
                              hipStream_t stream) {
    const float* x   = (const float*)d_in[0];
    const float* Wx0 = (const float*)d_in[1];
    const float* U0  = (const float*)d_in[2];
    const float* b0  = (const float*)d_in[3];
    const float* Wx1 = (const float*)d_in[4];
    const float* U1  = (const float*)d_in[5];
    const float* b1  = (const float*)d_in[6];
    const float* Wx2 = (const float*)d_in[7];
    const float* U2  = (const float*)d_in[8];
    const float* b2  = (const float*)d_in[9];
    const float* Wx3 = (const float*)d_in[10];
    const float* U3  = (const float*)d_in[11];
    const float* b3  = (const float*)d_in[12];
    const float* Wd  = (const float*)d_in[13];
    const float* bd  = (const float*)d_in[14];
    float* out = (float*)d_out;

    hipLaunchKernelGGL(lstm_fused, dim3(256), dim3(1024), 0, stream,
                       x, Wx0, U0, b0, Wx1, U1, b1, Wx2, U2, b2, Wx3, U3, b3,
                       Wd, bd, out);
}

// Round 3
// 7530.079 us; speedup vs baseline: 2.3585x; 2.3426x over previous
//
#include <hip/hip_runtime.h>
#include <stdint.h>

#define TT  512

__device__ __forceinline__ uint32_t f2bf(float f) {
    uint32_t u = __float_as_uint(f);
    return (u + 0x7FFFu + ((u >> 16) & 1u)) >> 16;   // RNE to bf16
}
__device__ __forceinline__ float sigm(float x) {
    float e = __builtin_amdgcn_exp2f(-1.4426950408889634f * x);
    return __builtin_amdgcn_rcpf(1.0f + e);
}
__device__ __forceinline__ float rdlane(float v, int k) {
    return __uint_as_float((uint32_t)__builtin_amdgcn_readlane((int)__float_as_uint(v), k));
}

#define REP32(M) M(0)M(1)M(2)M(3)M(4)M(5)M(6)M(7)M(8)M(9)M(10)M(11)M(12)M(13)M(14)M(15)M(16)M(17)M(18)M(19)M(20)M(21)M(22)M(23)M(24)M(25)M(26)M(27)M(28)M(29)M(30)M(31)

// weight regs as NAMED SCALARS: R1/R2 post-mortem showed u_pk[32]/w_pk[32]
// arrays were demoted to scratch (SROA runs before unroll, sees dynamic index)
// -> 44 GB of loop-invariant scratch re-reads/step. Named scalars must get VGPRs.
#define DECL_UW(i) uint32_t u##i, w##i;
#define LOAD_U(i)  { float a_ = Uw[(2*(i))*256 + g]; float b_ = Uw[(2*(i)+1)*256 + g]; u##i = f2bf(a_) | (f2bf(b_) << 16); }
#define LOAD_W(i)  { float a_ = Wxw[(2*(i))*256 + g]; float b_ = Wxw[(2*(i)+1)*256 + g]; w##i = f2bf(a_) | (f2bf(b_) << 16); }
#define ZERO_W(i)  w##i = 0u;

// recurrent matvec: h broadcast via v_readlane (SGPR), U column weights in VGPRs
#define FMA_U(i) { uint32_t w_ = u##i; float lo_ = __uint_as_float(w_ << 16); float hi_ = __uint_as_float(w_ & 0xffff0000u); \
    acc0 += rdlane(h0, 2*(i))   * lo_; acc1 += rdlane(h1, 2*(i))   * lo_; acc2 += rdlane(h2, 2*(i))   * lo_; acc3 += rdlane(h3, 2*(i))   * lo_; \
    acc0 += rdlane(h0, 2*(i)+1) * hi_; acc1 += rdlane(h1, 2*(i)+1) * hi_; acc2 += rdlane(h2, 2*(i)+1) * hi_; acc3 += rdlane(h3, 2*(i)+1) * hi_; }

// input matvec (layers 1..3): prev-layer h (xp*) broadcast, Wx columns in VGPRs
#define FMA_W(i) { uint32_t w_ = w##i; float lo_ = __uint_as_float(w_ << 16); float hi_ = __uint_as_float(w_ & 0xffff0000u); \
    acc0 += rdlane(xp0, 2*(i))   * lo_; acc1 += rdlane(xp1, 2*(i))   * lo_; acc2 += rdlane(xp2, 2*(i))   * lo_; acc3 += rdlane(xp3, 2*(i))   * lo_; \
    acc0 += rdlane(xp0, 2*(i)+1) * hi_; acc1 += rdlane(xp1, 2*(i)+1) * hi_; acc2 += rdlane(xp2, 2*(i)+1) * hi_; acc3 += rdlane(xp3, 2*(i)+1) * hi_; }

#define GATE(br) { \
    float zi_ = zl[((0*4 + br) << 6) + lane]; \
    float zf_ = zl[((1*4 + br) << 6) + lane]; \
    float zg_ = zl[((2*4 + br) << 6) + lane]; \
    float zo_ = zl[((3*4 + br) << 6) + lane]; \
    float c_  = sigm(zf_) * c##br + sigm(zi_) * fmaxf(zg_, 0.f); \
    h##br = sigm(zo_) * fmaxf(c_, 0.f); \
    c##br = c_; }

// 256 blocks x 1024 threads. Block owns 4 batch elements.
// Wave role: l = wave>>2 (layer), gi = wave&3 (gate group). Layer-pipelined:
// layer l works on local t = s - l; h handoff via LDS parity double-buffer.
__global__ __launch_bounds__(1024)
__attribute__((amdgpu_waves_per_eu(4, 4)))
void lstm_fused(
    const float* __restrict__ x,
    const float* __restrict__ Wx0, const float* __restrict__ U0, const float* __restrict__ b0,
    const float* __restrict__ Wx1, const float* __restrict__ U1, const float* __restrict__ b1,
    const float* __restrict__ Wx2, const float* __restrict__ U2, const float* __restrict__ b2,
    const float* __restrict__ Wx3, const float* __restrict__ U3, const float* __restrict__ b3,
    const float* __restrict__ Wd,  const float* __restrict__ bd,
    float* __restrict__ out)
{
    __shared__ float z_s[4 * 4 * 4 * 64];   // [l][gi][br][lane]  16 KB
    __shared__ float hb [4 * 2 * 4 * 64];   // [l][parity][br][lane] 8 KB
    __shared__ float x_s[4 * TT];           // 8 KB

    const int tid  = threadIdx.x;
    const int lane = tid & 63;
    const int wv   = tid >> 6;
    const int l    = wv >> 2;
    const int gi   = wv & 3;
    const int g    = (gi << 6) | lane;      // gate column in [0,256)
    const int b0i  = blockIdx.x * 4;

    for (int idx = tid; idx < 4 * TT; idx += 1024) {
        int br = idx >> 9, t = idx & (TT - 1);
        x_s[idx] = x[(b0i + br) * TT + t];
    }

    const float *Uw, *bw, *Wxw;
    if      (l == 0) { Uw = U0; bw = b0; Wxw = Wx0; }
    else if (l == 1) { Uw = U1; bw = b1; Wxw = Wx1; }
    else if (l == 2) { Uw = U2; bw = b2; Wxw = Wx2; }
    else             { Uw = U3; bw = b3; Wxw = Wx3; }

    REP32(DECL_UW)
    REP32(LOAD_U)
    if (l > 0) { REP32(LOAD_W) }
    else       { REP32(ZERO_W) }

    const float bias = bw[g];
    const float wx0w = (l == 0) ? Wxw[g] : 0.f;   // layer 0: F=1 scalar weight, fp32

    float h0 = 0.f, h1 = 0.f, h2 = 0.f, h3 = 0.f;
    float c0 = 0.f, c1 = 0.f, c2 = 0.f, c3 = 0.f;

    __syncthreads();

    for (int s = 0; s < TT + 3; ++s) {
        const int t = s - l;
        const bool active = (t >= 0) && (t < TT);

        if (active) {
            float acc0 = bias, acc1 = bias, acc2 = bias, acc3 = bias;

            if (l == 0) {
                acc0 += x_s[(0 << 9) + t] * wx0w;
                acc1 += x_s[(1 << 9) + t] * wx0w;
                acc2 += x_s[(2 << 9) + t] * wx0w;
                acc3 += x_s[(3 << 9) + t] * wx0w;
            } else {
                // prev layer's h at same local t (written last step, parity (s-1)&1)
                const float* src = hb + ((((l - 1) * 2 + ((s + 1) & 1)) * 4) << 6);
                float xp0 = src[(0 << 6) + lane];
                float xp1 = src[(1 << 6) + lane];
                float xp2 = src[(2 << 6) + lane];
                float xp3 = src[(3 << 6) + lane];
                REP32(FMA_W)
            }
            REP32(FMA_U)

            float* zw = z_s + (((l * 4 + gi) * 4) << 6);
            zw[(0 << 6) + lane] = acc0;
            zw[(1 << 6) + lane] = acc1;
            zw[(2 << 6) + lane] = acc2;
            zw[(3 << 6) + lane] = acc3;
        }

        __syncthreads();

        if (active) {
            // every wave of layer l redundantly combines gates for all 4 batch rows
            // (keeps h in every wave's registers -> readlane source next step)
            const float* zl = z_s + ((l * 16) << 6);
            GATE(0) GATE(1) GATE(2) GATE(3)

            if (l < 3) {
                float hgi = (gi == 0) ? h0 : (gi == 1) ? h1 : (gi == 2) ? h2 : h3;
                float* dst = hb + (((l * 2 + (s & 1)) * 4) << 6);
                dst[(gi << 6) + lane] = hgi;
            } else if (t == TT - 1) {
                float hgi = (gi == 0) ? h0 : (gi == 1) ? h1 : (gi == 2) ? h2 : h3;
                float v = hgi * Wd[lane];
                #pragma unroll
                for (int off = 32; off > 0; off >>= 1)
                    v += __shfl_down(v, off, 64);
                if (lane == 0) out[b0i + gi] = v + bd[0];
            }
        }

        __syncthreads();
    }
}

extern "C" void kernel_launch(void* const* d_in, const int* in_sizes, int n_in,
                              void* d_out, int out_size, void* d_ws, size_t ws_size,
                              hipStream_t stream) {
    const float* x   = (const float*)d_in[0];
    const float* Wx0 = (const float*)d_in[1];
    const float* U0  = (const float*)d_in[2];
    const float* b0  = (const float*)d_in[3];
    const float* Wx1 = (const float*)d_in[4];
    const float* U1  = (const float*)d_in[5];
    const float* b1  = (const float*)d_in[6];
    const float* Wx2 = (const float*)d_in[7];
    const float* U2  = (const float*)d_in[8];
    const float* b2  = (const float*)d_in[9];
    const float* Wx3 = (const float*)d_in[10];
    const float* U3  = (const float*)d_in[11];
    const float* b3  = (const float*)d_in[12];
    const float* Wd  = (const float*)d_in[13];
    const float* bd  = (const float*)d_in[14];
    float* out = (float*)d_out;

    hipLaunchKernelGGL(lstm_fused, dim3(256), dim3(1024), 0, stream,
                       x, Wx0, U0, b0, Wx1, U1, b1, Wx2, U2, b2, Wx3, U3, b3,
                       Wd, bd, out);
}

// Round 5
// 2336.111 us; speedup vs baseline: 7.6023x; 3.2233x over previous
//
#include <hip/hip_runtime.h>
#include <stdint.h>

#define TT 512

typedef _Float16 half2_t __attribute__((ext_vector_type(2)));
typedef __fp16   fp16x2  __attribute__((ext_vector_type(2)));

__device__ __forceinline__ uint32_t pkf16(float a, float b) {
    fp16x2 h = __builtin_amdgcn_cvt_pkrtz(a, b);
    return __builtin_bit_cast(uint32_t, h);
}
__device__ __forceinline__ float dot2(uint32_t w, uint32_t v, float c) {
#if __has_builtin(__builtin_amdgcn_fdot2)
    return __builtin_amdgcn_fdot2(__builtin_bit_cast(half2_t, w),
                                  __builtin_bit_cast(half2_t, v), c, false);
#else
    half2_t a = __builtin_bit_cast(half2_t, w);
    half2_t b = __builtin_bit_cast(half2_t, v);
    return c + (float)a.x * (float)b.x + (float)a.y * (float)b.y;
#endif
}
__device__ __forceinline__ uint32_t rdl(uint32_t v, int k) {
    return (uint32_t)__builtin_amdgcn_readlane((int)v, k);
}
__device__ __forceinline__ float sigm(float x) {
    float e = __builtin_amdgcn_exp2f(-1.4426950408889634f * x);
    return __builtin_amdgcn_rcpf(1.0f + e);
}

#define REP32(M) M(0)M(1)M(2)M(3)M(4)M(5)M(6)M(7)M(8)M(9)M(10)M(11)M(12)M(13)M(14)M(15)M(16)M(17)M(18)M(19)M(20)M(21)M(22)M(23)M(24)M(25)M(26)M(27)M(28)M(29)M(30)M(31)

// Recurrent U: thread-stationary packed f16 pairs (32 regs — fits the observed
// hard 64-VGPR budget; R1-R3 showed 64 weight regs always spill).
#define DECL_U(i) uint32_t u##i;
#define LOAD_U(i) { float a_ = Uw[(2*(i))*256 + g], b_ = Uw[(2*(i)+1)*256 + g]; u##i = pkf16(a_, b_); }

// u-side: 1 readlane (packed h pair) + 1 v_dot2 per (pair, batch-row)
#define DOT_U(i) { \
    acc0 = dot2(u##i, rdl(hk0, (i)), acc0); \
    acc1 = dot2(u##i, rdl(hk1, (i)), acc1); \
    acc2 = dot2(u##i, rdl(hk2, (i)), acc2); \
    acc3 = dot2(u##i, rdl(hk3, (i)), acc3); }

// w-side: Wx streamed from LDS (f16 pairs), one ds_read_b32 per pair
#define DOT_W(i) { uint32_t w_ = wrow[(i) * 256]; \
    acc0 = dot2(w_, rdl(xk0, (i)), acc0); \
    acc1 = dot2(w_, rdl(xk1, (i)), acc1); \
    acc2 = dot2(w_, rdl(xk2, (i)), acc2); \
    acc3 = dot2(w_, rdl(xk3, (i)), acc3); }

// LDS layout (dwords): wx [0,24576) | z_s [24576,28672) | hp [28672,29696) | x_s [29696,31744)
// total 126976 B dynamic shared.
#define WX_OFF 0
#define Z_OFF  24576
#define HP_OFF 28672
#define X_OFF  29696

// 256 blocks x 1024 threads, 4 batch rows/block. 16 waves = 4 layers x 4 gate
// groups, layer-pipelined (layer l at local t = s - l); h handoff AND packed-pair
// construction share one LDS buffer hp (write f16 per lane, read back as dword pairs).
__global__ __launch_bounds__(1024)
__attribute__((amdgpu_waves_per_eu(4, 4)))
void lstm_fused(
    const float* __restrict__ x,
    const float* __restrict__ Wx0, const float* __restrict__ U0, const float* __restrict__ b0,
    const float* __restrict__ Wx1, const float* __restrict__ U1, const float* __restrict__ b1,
    const float* __restrict__ Wx2, const float* __restrict__ U2, const float* __restrict__ b2,
    const float* __restrict__ Wx3, const float* __restrict__ U3, const float* __restrict__ b3,
    const float* __restrict__ Wd,  const float* __restrict__ bd,
    float* __restrict__ out)
{
    extern __shared__ uint32_t smem[];
    uint32_t* wx_dw = smem + WX_OFF;          // [l-1][kp(32)][g(256)] f16 pairs
    float*    z_s   = (float*)(smem + Z_OFF); // [l][gate][br][lane] f32
    uint32_t* hp_dw = smem + HP_OFF;          // [l][parity][br][32] f16 pairs
    _Float16* hp_h  = (_Float16*)hp_dw;
    float*    x_s   = (float*)(smem + X_OFF); // [br][t] f32

    const int tid  = threadIdx.x;
    const int lane = tid & 63;
    const int wv   = tid >> 6;
    const int l    = wv >> 2;
    const int gi   = wv & 3;
    const int g    = (gi << 6) | lane;        // gate column in [0,256)
    const int li   = lane & 31;
    const int b0i  = blockIdx.x * 4;

    // ---- staging ----
    hp_dw[tid & 1023] = 0;                                    // zero h state (1024 dwords)
    for (int idx = tid; idx < 4 * TT; idx += 1024) {
        int br = idx >> 9, t = idx & (TT - 1);
        x_s[idx] = x[(b0i + br) * TT + t];
    }
    for (int l2 = 1; l2 <= 3; ++l2) {
        const float* W = (l2 == 1) ? Wx1 : (l2 == 2) ? Wx2 : Wx3;
        for (int idx = tid; idx < 8192; idx += 1024) {
            int kp = idx >> 8, gg = idx & 255;
            wx_dw[(l2 - 1) * 8192 + idx] = pkf16(W[(2 * kp) * 256 + gg],
                                                 W[(2 * kp + 1) * 256 + gg]);
        }
    }

    const float *Uw, *bw;
    if      (l == 0) { Uw = U0; bw = b0; }
    else if (l == 1) { Uw = U1; bw = b1; }
    else if (l == 2) { Uw = U2; bw = b2; }
    else             { Uw = U3; bw = b3; }

    REP32(DECL_U)
    REP32(LOAD_U)
    const float bias = bw[g];
    const float wx0w = (l == 0) ? Wx0[g] : 0.f;   // layer 0: F=1, fp32 scalar weight

    float c0 = 0.f, c1 = 0.f, c2 = 0.f, c3 = 0.f; // cell state (f32, per batch row)

    __syncthreads();

    for (int s = 0; s < TT + 3; ++s) {
        const int t = s - l;
        const bool active = (t >= 0) && (t < TT);

        if (active) {
            const int par_r = (s + 1) & 1;        // slot written last step
            // recurrent h as packed f16 pairs (lane j holds pair j for j<32; j>=32 dup)
            const uint32_t* hr = hp_dw + ((l * 2 + par_r) * 4) * 32;
            uint32_t hk0 = hr[0 * 32 + li], hk1 = hr[1 * 32 + li];
            uint32_t hk2 = hr[2 * 32 + li], hk3 = hr[3 * 32 + li];

            float acc0 = bias, acc1 = bias, acc2 = bias, acc3 = bias;

            if (l == 0) {
                acc0 += x_s[(0 << 9) + t] * wx0w;
                acc1 += x_s[(1 << 9) + t] * wx0w;
                acc2 += x_s[(2 << 9) + t] * wx0w;
                acc3 += x_s[(3 << 9) + t] * wx0w;
            } else {
                const uint32_t* xr = hp_dw + (((l - 1) * 2 + par_r) * 4) * 32;
                uint32_t xk0 = xr[0 * 32 + li], xk1 = xr[1 * 32 + li];
                uint32_t xk2 = xr[2 * 32 + li], xk3 = xr[3 * 32 + li];
                const uint32_t* wrow = wx_dw + (l - 1) * 8192 + g;
                REP32(DOT_W)
            }
            REP32(DOT_U)

            float* zw = z_s + (((l * 4 + gi) * 4) << 6);
            zw[(0 << 6) + lane] = acc0;
            zw[(1 << 6) + lane] = acc1;
            zw[(2 << 6) + lane] = acc2;
            zw[(3 << 6) + lane] = acc3;
        }

        __syncthreads();

        if (active) {
            // redundant per-wave cell update for all 4 batch rows (c stays in regs);
            // h computed only for br==gi (the row this wave publishes)
            const float* zl = z_s + ((l * 16) << 6);
            {
                float zi_, zf_, zg_;
                zi_ = zl[((0 * 4 + 0) << 6) + lane]; zf_ = zl[((1 * 4 + 0) << 6) + lane]; zg_ = zl[((2 * 4 + 0) << 6) + lane];
                c0 = sigm(zf_) * c0 + sigm(zi_) * fmaxf(zg_, 0.f);
                zi_ = zl[((0 * 4 + 1) << 6) + lane]; zf_ = zl[((1 * 4 + 1) << 6) + lane]; zg_ = zl[((2 * 4 + 1) << 6) + lane];
                c1 = sigm(zf_) * c1 + sigm(zi_) * fmaxf(zg_, 0.f);
                zi_ = zl[((0 * 4 + 2) << 6) + lane]; zf_ = zl[((1 * 4 + 2) << 6) + lane]; zg_ = zl[((2 * 4 + 2) << 6) + lane];
                c2 = sigm(zf_) * c2 + sigm(zi_) * fmaxf(zg_, 0.f);
                zi_ = zl[((0 * 4 + 3) << 6) + lane]; zf_ = zl[((1 * 4 + 3) << 6) + lane]; zg_ = zl[((2 * 4 + 3) << 6) + lane];
                c3 = sigm(zf_) * c3 + sigm(zi_) * fmaxf(zg_, 0.f);
            }
            float zo_ = zl[((3 * 4 + gi) << 6) + lane];
            float cgi = (gi == 0) ? c0 : (gi == 1) ? c1 : (gi == 2) ? c2 : c3;
            float hgi = sigm(zo_) * fmaxf(cgi, 0.f);

            // publish h (f16) — pairs materialize when read back as dwords
            hp_h[(((l * 2 + (s & 1)) * 4 + gi) << 6) + lane] = (_Float16)hgi;

            if (l == 3 && t == TT - 1) {
                float v = hgi * Wd[lane];
                #pragma unroll
                for (int off = 32; off > 0; off >>= 1)
                    v += __shfl_down(v, off, 64);
                if (lane == 0) out[b0i + gi] = v + bd[0];
            }
        }

        __syncthreads();
    }
}

extern "C" void kernel_launch(void* const* d_in, const int* in_sizes, int n_in,
                              void* d_out, int out_size, void* d_ws, size_t ws_size,
                              hipStream_t stream) {
    const float* x   = (const float*)d_in[0];
    const float* Wx0 = (const float*)d_in[1];
    const float* U0  = (const float*)d_in[2];
    const float* b0  = (const float*)d_in[3];
    const float* Wx1 = (const float*)d_in[4];
    const float* U1  = (const float*)d_in[5];
    const float* b1  = (const float*)d_in[6];
    const float* Wx2 = (const float*)d_in[7];
    const float* U2  = (const float*)d_in[8];
    const float* b2  = (const float*)d_in[9];
    const float* Wx3 = (const float*)d_in[10];
    const float* U3  = (const float*)d_in[11];
    const float* b3  = (const float*)d_in[12];
    const float* Wd  = (const float*)d_in[13];
    const float* bd  = (const float*)d_in[14];
    float* out = (float*)d_out;

    static const int kLds = 31744 * 4;   // 126976 B dynamic LDS
    (void)hipFuncSetAttribute((const void*)lstm_fused,
                              hipFuncAttributeMaxDynamicSharedMemorySize, kLds);
    hipLaunchKernelGGL(lstm_fused, dim3(256), dim3(1024), kLds, stream,
                       x, Wx0, U0, b0, Wx1, U1, b1, Wx2, U2, b2, Wx3, U3, b3,
                       Wd, bd, out);
}

// Round 6
// 1479.210 us; speedup vs baseline: 12.0063x; 1.5793x over previous
//
#include <hip/hip_runtime.h>
#include <stdint.h>

#define TT 512

typedef _Float16 half2_t __attribute__((ext_vector_type(2)));
typedef __fp16   fp16x2  __attribute__((ext_vector_type(2)));
typedef uint32_t u32x4   __attribute__((ext_vector_type(4)));

__device__ __forceinline__ uint32_t pkf16(float a, float b) {
    fp16x2 h = __builtin_amdgcn_cvt_pkrtz(a, b);
    return __builtin_bit_cast(uint32_t, h);
}
__device__ __forceinline__ float dot2(uint32_t w, uint32_t v, float c) {
#if __has_builtin(__builtin_amdgcn_fdot2)
    return __builtin_amdgcn_fdot2(__builtin_bit_cast(half2_t, w),
                                  __builtin_bit_cast(half2_t, v), c, false);
#else
    half2_t a = __builtin_bit_cast(half2_t, w);
    half2_t b = __builtin_bit_cast(half2_t, v);
    return c + (float)a.x * (float)b.x + (float)a.y * (float)b.y;
#endif
}
__device__ __forceinline__ float sigm(float x) {
    float e = __builtin_amdgcn_exp2f(-1.4426950408889634f * x);
    return __builtin_amdgcn_rcpf(1.0f + e);
}

#define REP32(M) M(0)M(1)M(2)M(3)M(4)M(5)M(6)M(7)M(8)M(9)M(10)M(11)M(12)M(13)M(14)M(15)M(16)M(17)M(18)M(19)M(20)M(21)M(22)M(23)M(24)M(25)M(26)M(27)M(28)M(29)M(30)M(31)

// Recurrent U: thread-stationary packed f16 pairs (32 named scalars — fits the
// observed 64-VGPR budget; R1-R3: arrays OR >32 weight regs always spill).
#define DECL_U(i) uint32_t u##i;
#define LOAD_U(i) { float a_ = Uw[(2*(i))*256 + g], b_ = Uw[(2*(i)+1)*256 + g]; u##i = pkf16(a_, b_); }

// R5 post-mortem: 256 v_readlane/wave/step = half the VALU issue. Replace with
// wave-uniform ds_read_b128 (HW broadcast, 4 pairs/instr, conflict-free).
// 4 row-loads then 16 dot2 -> 4-way ILP across batch-row acc chains.
#define UJB(jb, wa, wb, wc, wd) { \
    u32x4 p0 = hr0[jb], p1 = hr1[jb], p2 = hr2[jb], p3 = hr3[jb]; \
    acc0 = dot2(wa, p0.x, acc0); acc1 = dot2(wa, p1.x, acc1); acc2 = dot2(wa, p2.x, acc2); acc3 = dot2(wa, p3.x, acc3); \
    acc0 = dot2(wb, p0.y, acc0); acc1 = dot2(wb, p1.y, acc1); acc2 = dot2(wb, p2.y, acc2); acc3 = dot2(wb, p3.y, acc3); \
    acc0 = dot2(wc, p0.z, acc0); acc1 = dot2(wc, p1.z, acc1); acc2 = dot2(wc, p2.z, acc2); acc3 = dot2(wc, p3.z, acc3); \
    acc0 = dot2(wd, p0.w, acc0); acc1 = dot2(wd, p1.w, acc1); acc2 = dot2(wd, p2.w, acc2); acc3 = dot2(wd, p3.w, acc3); }

// w-side: Wx columns streamed from LDS (lane-spread b32, conflict-free);
// x broadcasts via the same b128 scheme.
#define WJB(jb) { \
    u32x4 p0 = xr0[jb], p1 = xr1[jb], p2 = xr2[jb], p3 = xr3[jb]; \
    uint32_t wa = wrow[(4*(jb)+0)*256], wb = wrow[(4*(jb)+1)*256]; \
    uint32_t wc = wrow[(4*(jb)+2)*256], wd = wrow[(4*(jb)+3)*256]; \
    acc0 = dot2(wa, p0.x, acc0); acc1 = dot2(wa, p1.x, acc1); acc2 = dot2(wa, p2.x, acc2); acc3 = dot2(wa, p3.x, acc3); \
    acc0 = dot2(wb, p0.y, acc0); acc1 = dot2(wb, p1.y, acc1); acc2 = dot2(wb, p2.y, acc2); acc3 = dot2(wb, p3.y, acc3); \
    acc0 = dot2(wc, p0.z, acc0); acc1 = dot2(wc, p1.z, acc1); acc2 = dot2(wc, p2.z, acc2); acc3 = dot2(wc, p3.z, acc3); \
    acc0 = dot2(wd, p0.w, acc0); acc1 = dot2(wd, p1.w, acc1); acc2 = dot2(wd, p2.w, acc2); acc3 = dot2(wd, p3.w, acc3); }

// LDS layout (dwords): wx [0,24576) | z_s [24576,28672) | hp [28672,29696) | x_s [29696,31744)
#define WX_OFF 0
#define Z_OFF  24576
#define HP_OFF 28672
#define X_OFF  29696

// 256 blocks x 1024 threads, 4 batch rows/block. 16 waves = 4 layers x 4 gate
// groups, layer-pipelined (layer l at local t = s - l); h handoff via LDS hp
// (f16 per-lane writes, read back as broadcast dword pairs), parity dbuf.
__global__ __launch_bounds__(1024)
__attribute__((amdgpu_waves_per_eu(4, 4)))
void lstm_fused(
    const float* __restrict__ x,
    const float* __restrict__ Wx0, const float* __restrict__ U0, const float* __restrict__ b0,
    const float* __restrict__ Wx1, const float* __restrict__ U1, const float* __restrict__ b1,
    const float* __restrict__ Wx2, const float* __restrict__ U2, const float* __restrict__ b2,
    const float* __restrict__ Wx3, const float* __restrict__ U3, const float* __restrict__ b3,
    const float* __restrict__ Wd,  const float* __restrict__ bd,
    float* __restrict__ out)
{
    extern __shared__ uint32_t smem[];
    uint32_t* wx_dw = smem + WX_OFF;          // [l-1][kp(32)][g(256)] f16 pairs
    float*    z_s   = (float*)(smem + Z_OFF); // [l][gate][br][lane] f32
    uint32_t* hp_dw = smem + HP_OFF;          // [l][parity][br][32] f16 pairs
    _Float16* hp_h  = (_Float16*)hp_dw;
    float*    x_s   = (float*)(smem + X_OFF); // [br][t] f32

    const int tid  = threadIdx.x;
    const int lane = tid & 63;
    const int wv   = tid >> 6;
    const int l    = wv >> 2;
    const int gi   = wv & 3;
    const int g    = (gi << 6) | lane;        // gate column in [0,256)
    const int b0i  = blockIdx.x * 4;

    // ---- staging ----
    hp_dw[tid & 1023] = 0;                    // zero h state (1024 dwords)
    for (int idx = tid; idx < 4 * TT; idx += 1024) {
        int br = idx >> 9, t = idx & (TT - 1);
        x_s[idx] = x[(b0i + br) * TT + t];
    }
    for (int l2 = 1; l2 <= 3; ++l2) {
        const float* W = (l2 == 1) ? Wx1 : (l2 == 2) ? Wx2 : Wx3;
        for (int idx = tid; idx < 8192; idx += 1024) {
            int kp = idx >> 8, gg = idx & 255;
            wx_dw[(l2 - 1) * 8192 + idx] = pkf16(W[(2 * kp) * 256 + gg],
                                                 W[(2 * kp + 1) * 256 + gg]);
        }
    }

    const float *Uw, *bw;
    if      (l == 0) { Uw = U0; bw = b0; }
    else if (l == 1) { Uw = U1; bw = b1; }
    else if (l == 2) { Uw = U2; bw = b2; }
    else             { Uw = U3; bw = b3; }

    REP32(DECL_U)
    REP32(LOAD_U)
    const float bias = bw[g];
    const float wx0w = (l == 0) ? Wx0[g] : 0.f;   // layer 0: F=1, fp32 scalar weight

    float cg = 0.f;                                // cell state, own row (gi) only

    __syncthreads();

    for (int s = 0; s < TT + 3; ++s) {
        const int t = s - l;
        const bool active = (t >= 0) && (t < TT);

        if (active) {
            const int par_r = (s + 1) & 1;        // slot written last step
            const u32x4* hr0 = (const u32x4*)(hp_dw + ((l * 2 + par_r) * 4) * 32);
            const u32x4* hr1 = hr0 + 8;
            const u32x4* hr2 = hr0 + 16;
            const u32x4* hr3 = hr0 + 24;

            float acc0 = bias, acc1 = bias, acc2 = bias, acc3 = bias;

            if (l == 0) {
                acc0 += x_s[(0 << 9) + t] * wx0w;
                acc1 += x_s[(1 << 9) + t] * wx0w;
                acc2 += x_s[(2 << 9) + t] * wx0w;
                acc3 += x_s[(3 << 9) + t] * wx0w;
            } else {
                const u32x4* xr0 = (const u32x4*)(hp_dw + (((l - 1) * 2 + par_r) * 4) * 32);
                const u32x4* xr1 = xr0 + 8;
                const u32x4* xr2 = xr0 + 16;
                const u32x4* xr3 = xr0 + 24;
                const uint32_t* wrow = wx_dw + (l - 1) * 8192 + g;
                WJB(0) WJB(1) WJB(2) WJB(3) WJB(4) WJB(5) WJB(6) WJB(7)
            }
            UJB(0, u0,  u1,  u2,  u3)  UJB(1, u4,  u5,  u6,  u7)
            UJB(2, u8,  u9,  u10, u11) UJB(3, u12, u13, u14, u15)
            UJB(4, u16, u17, u18, u19) UJB(5, u20, u21, u22, u23)
            UJB(6, u24, u25, u26, u27) UJB(7, u28, u29, u30, u31)

            float* zw = z_s + (((l * 4 + gi) * 4) << 6);
            zw[(0 << 6) + lane] = acc0;
            zw[(1 << 6) + lane] = acc1;
            zw[(2 << 6) + lane] = acc2;
            zw[(3 << 6) + lane] = acc3;
        }

        __syncthreads();

        if (active) {
            // gate math for OWN row (gi) only — h comes from LDS now, so no wave
            // needs other rows' h in registers (R5's redundant 4-row combine dropped)
            const float* zl = z_s + ((l * 16) << 6);
            float zi_ = zl[((0 * 4 + gi) << 6) + lane];
            float zf_ = zl[((1 * 4 + gi) << 6) + lane];
            float zg_ = zl[((2 * 4 + gi) << 6) + lane];
            float zo_ = zl[((3 * 4 + gi) << 6) + lane];
            cg = sigm(zf_) * cg + sigm(zi_) * fmaxf(zg_, 0.f);
            float hgi = sigm(zo_) * fmaxf(cg, 0.f);

            hp_h[(((l * 2 + (s & 1)) * 4 + gi) << 6) + lane] = (_Float16)hgi;

            if (l == 3 && t == TT - 1) {
                float v = hgi * Wd[lane];
                #pragma unroll
                for (int off = 32; off > 0; off >>= 1)
                    v += __shfl_down(v, off, 64);
                if (lane == 0) out[b0i + gi] = v + bd[0];
            }
        }

        __syncthreads();
    }
}

extern "C" void kernel_launch(void* const* d_in, const int* in_sizes, int n_in,
                              void* d_out, int out_size, void* d_ws, size_t ws_size,
                              hipStream_t stream) {
    const float* x   = (const float*)d_in[0];
    const float* Wx0 = (const float*)d_in[1];
    const float* U0  = (const float*)d_in[2];
    const float* b0  = (const float*)d_in[3];
    const float* Wx1 = (const float*)d_in[4];
    const float* U1  = (const float*)d_in[5];
    const float* b1  = (const float*)d_in[6];
    const float* Wx2 = (const float*)d_in[7];
    const float* U2  = (const float*)d_in[8];
    const float* b2  = (const float*)d_in[9];
    const float* Wx3 = (const float*)d_in[10];
    const float* U3  = (const float*)d_in[11];
    const float* b3  = (const float*)d_in[12];
    const float* Wd  = (const float*)d_in[13];
    const float* bd  = (const float*)d_in[14];
    float* out = (float*)d_out;

    static const int kLds = 31744 * 4;   // 126976 B dynamic LDS
    (void)hipFuncSetAttribute((const void*)lstm_fused,
                              hipFuncAttributeMaxDynamicSharedMemorySize, kLds);
    hipLaunchKernelGGL(lstm_fused, dim3(256), dim3(1024), kLds, stream,
                       x, Wx0, U0, b0, Wx1, U1, b1, Wx2, U2, b2, Wx3, U3, b3,
                       Wd, bd, out);
}

// Round 7
// 873.563 us; speedup vs baseline: 20.3304x; 1.6933x over previous
//
#include <hip/hip_runtime.h>
#include <stdint.h>

#define TT 512

typedef __fp16 f16x8 __attribute__((ext_vector_type(8)));
typedef float  f32x4 __attribute__((ext_vector_type(4)));

__device__ __forceinline__ float sigm(float x) {
    float e = __builtin_amdgcn_exp2f(-1.4426950408889634f * x);
    return __builtin_amdgcn_rcpf(1.0f + e);
}
__device__ __forceinline__ f32x4 mfma16(f16x8 a, f16x8 b, f32x4 c) {
    return __builtin_amdgcn_mfma_f32_16x16x32_f16(a, b, c, 0, 0, 0);
}

#define REP8(M) M(0)M(1)M(2)M(3)M(4)M(5)M(6)M(7)

// Gather one B-operand fragment from global: B[k = quad*8+j][n = col], k-stride 256.
// One-time setup cost; lands in named VGPRs (no arrays -> no SROA scratch, per R1-R3).
#define GATH(SRC, col, kf) \
  (f16x8){ (__fp16)(SRC)[((kf)*32 + quad*8 + 0)*256 + (col)], \
           (__fp16)(SRC)[((kf)*32 + quad*8 + 1)*256 + (col)], \
           (__fp16)(SRC)[((kf)*32 + quad*8 + 2)*256 + (col)], \
           (__fp16)(SRC)[((kf)*32 + quad*8 + 3)*256 + (col)], \
           (__fp16)(SRC)[((kf)*32 + quad*8 + 4)*256 + (col)], \
           (__fp16)(SRC)[((kf)*32 + quad*8 + 5)*256 + (col)], \
           (__fp16)(SRC)[((kf)*32 + quad*8 + 6)*256 + (col)], \
           (__fp16)(SRC)[((kf)*32 + quad*8 + 7)*256 + (col)] }

// Tile T = gate*2 + q; cols [gate*64 + half*32 + q*16, +16). Weights thread-resident.
#define DECLW(T) f16x8 ub##T##_0, ub##T##_1, wb##T##_0, wb##T##_1; float bias##T, wx0##T;
#define LOADW(T) { const int colT = (((T)>>1)<<6) + (half<<5) + (((T)&1)<<4) + l15; \
    ub##T##_0 = GATH(Uw,   colT, 0); ub##T##_1 = GATH(Uw,   colT, 1); \
    wb##T##_0 = GATH(Wsrc, colT, 0); wb##T##_1 = GATH(Wsrc, colT, 1); \
    bias##T = bw_[colT]; wx0##T = Wx0[colT]; }

#define HMM(T) f32x4 a##T = (f32x4){bias##T, bias##T, bias##T, bias##T}; \
    a##T = mfma16(hA0, ub##T##_0, a##T); a##T = mfma16(hA1, ub##T##_1, a##T);
#define XMM(T) a##T = mfma16(xA0, wb##T##_0, a##T); a##T = mfma16(xA1, wb##T##_1, a##T);
#define X0F(T) a##T += xv * wx0##T;

// Gates land in identical C-layout slots across tiles -> fully in-register update.
#define GQ(q, Ti, Tf, Tg, To, cv, hv) { \
    _Pragma("unroll") for (int r = 0; r < 4; ++r) { \
        float ci = sigm(a##Tf[r]) * cv[r] + sigm(a##Ti[r]) * fmaxf((float)(a##Tg[r]), 0.f); \
        cv[r] = ci; \
        float hh = sigm(a##To[r]) * fmaxf(ci, 0.f); \
        hv[r] = hh; \
        hwp[r * 72 + (q)*16] = (_Float16)hh; \
    } }

// 64 blocks x 512 threads; block = 16 batch rows (MFMA M=16). 8 waves =
// 4 layers x 2 unit-halves, layer-pipelined (layer l at t = s - l).
// ONE barrier/step: z never leaves registers; h handoff via parity-dbuf LDS.
// 512-thr block + waves_per_eu(2,2) -> 256-VGPR budget for ~210 live regs
// (the 1024-thr shape was hard-capped at 64 VGPRs in R1-R3).
__global__ __launch_bounds__(512)
__attribute__((amdgpu_waves_per_eu(2, 2)))
void lstm_mfma(
    const float* __restrict__ x,
    const float* __restrict__ Wx0, const float* __restrict__ U0, const float* __restrict__ b0,
    const float* __restrict__ Wx1, const float* __restrict__ U1, const float* __restrict__ b1,
    const float* __restrict__ Wx2, const float* __restrict__ U2, const float* __restrict__ b2,
    const float* __restrict__ Wx3, const float* __restrict__ U3, const float* __restrict__ b3,
    const float* __restrict__ Wd,  const float* __restrict__ bd,
    float* __restrict__ out)
{
    __shared__ _Float16 hbuf_h[4 * 2 * 16 * 72];  // [l][parity][row 16][unit 64 pad 72]
    __shared__ float    x_s[TT][16];              // [t][row]
    __shared__ float    red[16][32];              // dense-epilogue partials

    const int tid  = threadIdx.x;
    const int lane = tid & 63;
    const int l15  = lane & 15;
    const int quad = lane >> 4;
    const int wv   = tid >> 6;
    const int l    = wv >> 1;
    const int half = wv & 1;
    const int b0i  = blockIdx.x * 16;

    // ---- staging ----
    for (int i = tid; i < 4 * 2 * 16 * 72 / 2; i += 512)
        ((uint32_t*)hbuf_h)[i] = 0;
    for (int idx = tid; idx < 16 * TT; idx += 512) {
        int row = idx >> 9, t = idx & (TT - 1);
        x_s[t][row] = x[(b0i + row) * TT + t];
    }

    const float* Uw  = (l == 0) ? U0 : (l == 1) ? U1 : (l == 2) ? U2 : U3;
    const float* bw_ = (l == 0) ? b0 : (l == 1) ? b1 : (l == 2) ? b2 : b3;
    // l==0 has no Wx MFMA; point at U0 (in-bounds dummy) so the gather is safe.
    const float* Wsrc = (l == 1) ? Wx1 : (l == 2) ? Wx2 : (l == 3) ? Wx3 : U0;

    REP8(DECLW)
    REP8(LOADW)
    const float wd0 = Wd[(half << 5) + l15];
    const float wd1 = Wd[(half << 5) + 16 + l15];

    f32x4 c0 = {0.f, 0.f, 0.f, 0.f};
    f32x4 c1 = {0.f, 0.f, 0.f, 0.f};

    __syncthreads();

    for (int s = 0; s < TT + 3; ++s) {
        const int t = s - l;
        if (t >= 0 && t < TT) {
            const int par_r = (s + 1) & 1;
            const int par_w = s & 1;

            // A-frags: A[m=l15][k=quad*8+j], rows stride 72 f16 (144 B, 16B-aligned)
            const _Float16* hb_own = hbuf_h + (l * 2 + par_r) * 1152;
            f16x8 hA0 = *(const f16x8*)(hb_own + l15 * 72 + quad * 8);
            f16x8 hA1 = *(const f16x8*)(hb_own + l15 * 72 + 32 + quad * 8);

            REP8(HMM)

            if (l == 0) {
                f32x4 xv = { x_s[t][quad * 4 + 0], x_s[t][quad * 4 + 1],
                             x_s[t][quad * 4 + 2], x_s[t][quad * 4 + 3] };
                REP8(X0F)
            } else {
                const _Float16* hb_in = hbuf_h + ((l - 1) * 2 + par_r) * 1152;
                f16x8 xA0 = *(const f16x8*)(hb_in + l15 * 72 + quad * 8);
                f16x8 xA1 = *(const f16x8*)(hb_in + l15 * 72 + 32 + quad * 8);
                REP8(XMM)
            }

            // gate + h publish (C layout: row=quad*4+r, col=l15)
            _Float16* hwp = hbuf_h + (l * 2 + par_w) * 1152 + (quad * 4) * 72
                          + (half << 5) + l15;
            f32x4 h0v, h1v;
            GQ(0, 0, 2, 4, 6, c0, h0v)
            GQ(1, 1, 3, 5, 7, c1, h1v)

            if (l == 3 && t == TT - 1) {
                #pragma unroll
                for (int r = 0; r < 4; ++r)
                    red[quad * 4 + r][(half << 4) + l15] = h0v[r] * wd0 + h1v[r] * wd1;
            }
        }
        __syncthreads();
    }

    // dense epilogue: wave (l=3, half=0), lanes 0..15 each own one batch row
    if (wv == 6 && lane < 16) {
        float s_ = bd[0];
        #pragma unroll
        for (int j = 0; j < 32; ++j) s_ += red[lane][j];
        out[b0i + lane] = s_;
    }
}

extern "C" void kernel_launch(void* const* d_in, const int* in_sizes, int n_in,
                              void* d_out, int out_size, void* d_ws, size_t ws_size,
                              hipStream_t stream) {
    const float* x   = (const float*)d_in[0];
    const float* Wx0 = (const float*)d_in[1];
    const float* U0  = (const float*)d_in[2];
    const float* b0  = (const float*)d_in[3];
    const float* Wx1 = (const float*)d_in[4];
    const float* U1  = (const float*)d_in[5];
    const float* b1  = (const float*)d_in[6];
    const float* Wx2 = (const float*)d_in[7];
    const float* U2  = (const float*)d_in[8];
    const float* b2  = (const float*)d_in[9];
    const float* Wx3 = (const float*)d_in[10];
    const float* U3  = (const float*)d_in[11];
    const float* b3  = (const float*)d_in[12];
    const float* Wd  = (const float*)d_in[13];
    const float* bd  = (const float*)d_in[14];
    float* out = (float*)d_out;

    hipLaunchKernelGGL(lstm_mfma, dim3(64), dim3(512), 0, stream,
                       x, Wx0, U0, b0, Wx1, U1, b1, Wx2, U2, b2, Wx3, U3, b3,
                       Wd, bd, out);
}